// Round 5
// baseline (2302.665 us; speedup 1.0000x reference)
//
#include <hip/hip_runtime.h>

typedef _Float16 v8h __attribute__((ext_vector_type(8)));
typedef float    v4f __attribute__((ext_vector_type(4)));

#define LO_SCALE 2048.0f
#define LO_INV   4.8828125e-4f

__device__ __forceinline__ float fast_rcp(float x) { return __builtin_amdgcn_rcpf(x); }
__device__ __forceinline__ float sigmoid_f(float x) { return fast_rcp(1.0f + __expf(-x)); }
__device__ __forceinline__ float tanh_f(float x) {
    float e = __expf(-2.0f * fabsf(x));
    float r = (1.0f - e) * fast_rcp(1.0f + e);
    return copysignf(r, x);
}

// ---------------------------------------------------------------------------
// prep: fused f16 weight matrix, STREAM-PACKED for the recur bf loads:
// WTp[g][ksl(4)][ks(14)][quad(4)][col(16)][j(8)] -> each wave bf load = 1KB
// contiguous. Logical source: WT[g][kout=ksl*16+col][k=ks*32+quad*8+j] with
// K segments [Wt0|Wt1|Wt2|Ws|U|Zt|Zs[ZS_IDX[g]]].
// ---------------------------------------------------------------------------
__global__ void prep_wt(const float* __restrict__ Wt, const float* __restrict__ Ws,
                        const float* __restrict__ U,  const float* __restrict__ Zt,
                        const float* __restrict__ Zs, _Float16* __restrict__ WTp)
{
    int idx = blockIdx.x * 256 + threadIdx.x;
    if (idx >= 9 * 4 * 14 * 512) return;          // 258048
    int j    = idx & 7;
    int col  = (idx >> 3) & 15;
    int quad = (idx >> 7) & 3;
    int gksl = idx / 7168;
    int ks   = (idx - gksl * 7168) >> 9;
    int g    = gksl >> 2;
    int ksl  = gksl & 3;
    int kout = ksl * 16 + col;
    int k    = ks * 32 + quad * 8 + j;
    int seg  = k >> 6, kl = k & 63;
    const int zsidx[9] = {0, 1, 1, 3, 4, 5, 6, 7, 8};
    float v;
    if (seg < 3)       v = Wt[g * 12288 + (seg * 64 + kl) * 64 + kout];
    else if (seg == 3) v = Ws[g * 4096 + kl * 64 + kout];
    else if (seg == 4) v = U [g * 4096 + kl * 64 + kout];
    else if (seg == 5) v = Zt[g * 4096 + kl * 64 + kout];
    else               v = Zs[zsidx[g] * 4096 + kl * 64 + kout];
    WTp[idx] = (_Float16)v;
}

// ---------------------------------------------------------------------------
// zero-fill the f16 zero tile (edge pad for h(t+-1) / c(t+-1) reads)
// ---------------------------------------------------------------------------
__global__ void zfill(_Float16* __restrict__ Z)
{
    int i = (blockIdx.x * 256 + threadIdx.x) * 8;   // 2 blocks x 256 x 8 = 4096
    v8h z;
#pragma unroll
    for (int j = 0; j < 8; ++j) z[j] = (_Float16)0.0f;
    *(v8h*)(Z + i) = z;
}

// ---------------------------------------------------------------------------
// f32 -> f16 hi/lo split of encoder inputs, zero-padded to 2048 rows
// ---------------------------------------------------------------------------
__global__ void conv_enc(const float* __restrict__ X,
                         _Float16* __restrict__ Yh, _Float16* __restrict__ Yl)
{
    long i = ((long)blockIdx.x * 256 + threadIdx.x) * 8;   // < 2048*4096
    v8h oh, ol;
    if (i < 2016L * 4096) {
        const float4* p = (const float4*)(X + i);
        float4 a = p[0], b = p[1];
        float xv[8] = {a.x, a.y, a.z, a.w, b.x, b.y, b.z, b.w};
#pragma unroll
        for (int j = 0; j < 8; ++j) {
            _Float16 hi = (_Float16)xv[j];
            oh[j] = hi;
            ol[j] = (_Float16)((xv[j] - (float)hi) * LO_SCALE);
        }
    } else {
#pragma unroll
        for (int j = 0; j < 8; ++j) { oh[j] = (_Float16)0.0f; ol[j] = (_Float16)0.0f; }
    }
    *(v8h*)(Yh + i) = oh;
    *(v8h*)(Yl + i) = ol;
}

// ---------------------------------------------------------------------------
// transpose weights_in [k][n] f32 -> winT hi/lo [n][k] f16
// ---------------------------------------------------------------------------
__global__ void transp_win(const float* __restrict__ W,
                           _Float16* __restrict__ Th, _Float16* __restrict__ Tl)
{
    __shared__ float tile[64][65];
    int k0 = blockIdx.x * 64, n0 = blockIdx.y * 64;
    int tid = threadIdx.x;
    int cc = tid & 63;
#pragma unroll
    for (int p = 0; p < 16; ++p) {
        int r = p * 4 + (tid >> 6);
        tile[cc][r] = W[(size_t)(k0 + r) * 4096 + n0 + cc];
    }
    __syncthreads();
#pragma unroll
    for (int p = 0; p < 16; ++p) {
        int r = p * 4 + (tid >> 6);
        float v = tile[r][cc];
        _Float16 hi = (_Float16)v;
        Th[(size_t)(n0 + r) * 4096 + k0 + cc] = hi;
        Tl[(size_t)(n0 + r) * 4096 + k0 + cc] = (_Float16)((v - (float)hi) * LO_SCALE);
    }
}

// ---------------------------------------------------------------------------
// h0 = enc @ winT^T + bias, compensated 3-pass f16 MFMA (f32-exact result)
// 128x128 tile, BK=32; writes f32 (c0, for means) and f16 (hA)
// ---------------------------------------------------------------------------
__global__ __launch_bounds__(256, 2) void gemm_h0(
    const _Float16* __restrict__ Ah, const _Float16* __restrict__ Al,
    const _Float16* __restrict__ Bh, const _Float16* __restrict__ Bl,
    const float* __restrict__ bias, float* __restrict__ h0f, _Float16* __restrict__ h0h)
{
    __shared__ __attribute__((aligned(16))) _Float16 Ash[128 * 40];
    __shared__ __attribute__((aligned(16))) _Float16 Asl[128 * 40];
    __shared__ __attribute__((aligned(16))) _Float16 Bsh[128 * 40];
    __shared__ __attribute__((aligned(16))) _Float16 Bsl[128 * 40];
    int id = blockIdx.x;                 // 0..511
    int xcd = id & 7, local = id >> 3;   // local 0..63
    int nt = xcd * 4 + (local >> 4);     // 0..31
    int mt = local & 15;                 // 0..15
    int tid = threadIdx.x, wave = tid >> 6, lane = tid & 63;
    int col = lane & 15, quad = lane >> 4;

    v4f accm[2][8], accc[2][8];
#pragma unroll
    for (int mi = 0; mi < 2; ++mi)
#pragma unroll
        for (int ni = 0; ni < 8; ++ni) {
            v4f z = {0.f, 0.f, 0.f, 0.f};
            accm[mi][ni] = z; accc[mi][ni] = z;
        }

    for (int kt = 0; kt < 128; ++kt) {
        __syncthreads();
#pragma unroll
        for (int p = 0; p < 2; ++p) {
            int idx = p * 2048 + tid * 8;
            int r = idx >> 5, c = idx & 31;
            size_t ga = (size_t)(mt * 128 + r) * 4096 + kt * 32 + c;
            size_t gb = (size_t)(nt * 128 + r) * 4096 + kt * 32 + c;
            *(v8h*)(&Ash[r * 40 + c]) = *(const v8h*)(Ah + ga);
            *(v8h*)(&Asl[r * 40 + c]) = *(const v8h*)(Al + ga);
            *(v8h*)(&Bsh[r * 40 + c]) = *(const v8h*)(Bh + gb);
            *(v8h*)(&Bsl[r * 40 + c]) = *(const v8h*)(Bl + gb);
        }
        __syncthreads();
        v8h afh[2], afl[2];
#pragma unroll
        for (int mi = 0; mi < 2; ++mi) {
            afh[mi] = *(const v8h*)(&Ash[(wave * 32 + mi * 16 + col) * 40 + quad * 8]);
            afl[mi] = *(const v8h*)(&Asl[(wave * 32 + mi * 16 + col) * 40 + quad * 8]);
        }
#pragma unroll
        for (int ni = 0; ni < 8; ++ni) {
            v8h bfh = *(const v8h*)(&Bsh[(ni * 16 + col) * 40 + quad * 8]);
            v8h bfl = *(const v8h*)(&Bsl[(ni * 16 + col) * 40 + quad * 8]);
#pragma unroll
            for (int mi = 0; mi < 2; ++mi) {
                accm[mi][ni] = __builtin_amdgcn_mfma_f32_16x16x32_f16(afh[mi], bfh, accm[mi][ni], 0, 0, 0);
                accc[mi][ni] = __builtin_amdgcn_mfma_f32_16x16x32_f16(afl[mi], bfh, accc[mi][ni], 0, 0, 0);
                accc[mi][ni] = __builtin_amdgcn_mfma_f32_16x16x32_f16(afh[mi], bfl, accc[mi][ni], 0, 0, 0);
            }
        }
    }
#pragma unroll
    for (int mi = 0; mi < 2; ++mi)
#pragma unroll
        for (int ni = 0; ni < 8; ++ni)
#pragma unroll
            for (int i = 0; i < 4; ++i) {
                int row  = mt * 128 + wave * 32 + mi * 16 + quad * 4 + i;
                int ccol = nt * 128 + ni * 16 + col;
                if (row < 2016) {
                    float v = accm[mi][ni][i] + accc[mi][ni][i] * LO_INV + bias[ccol];
                    h0f[(size_t)row * 4096 + ccol] = v;
                    h0h[(size_t)row * 4096 + ccol] = (_Float16)v;
                }
            }
}

// ---------------------------------------------------------------------------
// g_t = mean over t (63);  g_s = mean over n (64)
// ---------------------------------------------------------------------------
__global__ void mean_t(const float* __restrict__ h0, float* __restrict__ gt32,
                       _Float16* __restrict__ gt16)
{
    int i = blockIdx.x * 256 + threadIdx.x;       // < 32*4096
    int b = i >> 12, c = i & 4095;
    float s = 0.f;
    for (int t = 0; t < 63; ++t) s += h0[((size_t)b * 63 + t) * 4096 + c];
    s *= (1.0f / 63.0f);
    gt32[i] = s; gt16[i] = (_Float16)s;
}

__global__ void mean_n(const float* __restrict__ h0, float* __restrict__ gs32,
                       _Float16* __restrict__ gs16)
{
    int i = blockIdx.x * 256 + threadIdx.x;       // < 2016*64
    int row = i >> 6, k = i & 63;
    float s = 0.f;
    for (int n = 0; n < 64; ++n) s += h0[(size_t)row * 4096 + n * 64 + k];
    s *= (1.0f / 64.0f);
    gs32[i] = s; gs16[i] = (_Float16)s;
}

// ---------------------------------------------------------------------------
// fused recurrent step, k-split, minimal-LDS, stream-packed weights.
// Block = 4 waves per (b,t); wave owns k-slice [wave*16, wave*16+16).
// Only h(t) staged in LDS (zero row 0 for the n-shift); all other A segments
// read direct from global (full-line utilization, L2-resident).
// c ping-pong is f16. One barrier, no atomics.
// ---------------------------------------------------------------------------
__global__ __launch_bounds__(256, 4) void recur(
    const _Float16* __restrict__ h_in, _Float16* __restrict__ h_out,
    const _Float16* __restrict__ c_in, _Float16* __restrict__ c_out,
    const _Float16* __restrict__ p16, const _Float16* __restrict__ gt16,
    const _Float16* __restrict__ gs16, const float* __restrict__ gt32,
    const float* __restrict__ gs32, const _Float16* __restrict__ WTp,
    const float* __restrict__ bias9, const _Float16* __restrict__ ztile,
    float* __restrict__ outf, int last)
{
    __shared__ __attribute__((aligned(16))) _Float16 lds_h[65 * 72];  // row 0 = zeros

    int blk = blockIdx.x;
    int b = blk / 63, t = blk - b * 63;
    size_t toff = (size_t)blk * 4096;
    int tid = threadIdx.x;
    int wave = tid >> 6, lane = tid & 63;
    int col = lane & 15, quad = lane >> 4;
    int k0 = wave * 16;                  // this wave's k-slice; ksl == wave

    // ---- stage h(t) into LDS (stride 72: 2-way bank alias = free)
#pragma unroll
    for (int p2 = 0; p2 < 2; ++p2) {
        int idx = p2 * 2048 + tid * 8;
        int r = idx >> 6, c = idx & 63;
        *(v8h*)(&lds_h[(r + 1) * 72 + c]) = *(const v8h*)(h_in + toff + idx);
    }
    if (tid < 8) {
        v8h z;
#pragma unroll
        for (int j = 0; j < 8; ++j) z[j] = (_Float16)0.0f;
        *(v8h*)(&lds_h[tid * 8]) = z;
    }
    __syncthreads();

    const _Float16* hb  = (t > 0)  ? h_in + toff - 4096 : ztile;
    const _Float16* ha  = (t < 62) ? h_in + toff + 4096 : ztile;
    const _Float16* pp  = p16 + toff;
    const _Float16* gtb = gt16 + (size_t)b * 4096;
    const _Float16* gsb = gs16 + (size_t)blk * 64;
    const _Float16* ctb = (t > 0)  ? c_in + toff - 4096 : ztile;
    const _Float16* cta = (t < 62) ? c_in + toff + 4096 : ztile;
    const _Float16* cc  = c_in + toff;

    v4f csum[4], istash[4];
#pragma unroll
    for (int mi = 0; mi < 4; ++mi) {
        v4f z = {0.f, 0.f, 0.f, 0.f};
        csum[mi] = z; istash[mi] = z;
    }

    // gate order: 0(i), 1..6(forget), 8(c_n*i), 7(o -> h)
#pragma unroll
    for (int gi = 0; gi < 9; ++gi) {
        int g = (gi == 7) ? 8 : ((gi == 8) ? 7 : gi);
        const _Float16* wg = WTp + (size_t)(g * 4 + wave) * 7168;
        const float* bg = bias9 + g * 4096;

        v4f acc[4];
#pragma unroll
        for (int mi = 0; mi < 4; ++mi)
#pragma unroll
            for (int i = 0; i < 4; ++i)
                acc[mi][i] = bg[(mi * 16 + quad * 4 + i) * 64 + k0 + col];

#pragma unroll
        for (int ks = 0; ks < 14; ++ks) {
            int seg  = ks >> 1;
            int koff = (ks & 1) * 32 + quad * 8;
            v8h bf = *(const v8h*)(wg + ks * 512 + quad * 128 + col * 8);
            v8h af[4];
            if (seg == 0) {
#pragma unroll
                for (int mi = 0; mi < 4; ++mi)
                    af[mi] = *(const v8h*)(hb + (mi * 16 + col) * 64 + koff);
            } else if (seg == 1) {
#pragma unroll
                for (int mi = 0; mi < 4; ++mi)
                    af[mi] = *(const v8h*)(&lds_h[(mi * 16 + col + 1) * 72 + koff]);
            } else if (seg == 2) {
#pragma unroll
                for (int mi = 0; mi < 4; ++mi)
                    af[mi] = *(const v8h*)(ha + (mi * 16 + col) * 64 + koff);
            } else if (seg == 3) {       // h(n-1): shifted row, row 0 = zeros
#pragma unroll
                for (int mi = 0; mi < 4; ++mi)
                    af[mi] = *(const v8h*)(&lds_h[(mi * 16 + col) * 72 + koff]);
            } else if (seg == 4) {
#pragma unroll
                for (int mi = 0; mi < 4; ++mi)
                    af[mi] = *(const v8h*)(pp + (mi * 16 + col) * 64 + koff);
            } else if (seg == 5) {
#pragma unroll
                for (int mi = 0; mi < 4; ++mi)
                    af[mi] = *(const v8h*)(gtb + (mi * 16 + col) * 64 + koff);
            } else {
                v8h gv = *(const v8h*)(gsb + koff);     // broadcast over rows
#pragma unroll
                for (int mi = 0; mi < 4; ++mi) af[mi] = gv;
            }
#pragma unroll
            for (int mi = 0; mi < 4; ++mi)
                acc[mi] = __builtin_amdgcn_mfma_f32_16x16x32_f16(af[mi], bf, acc[mi], 0, 0, 0);
        }

        // ---- epilogue for this gate (g is compile-time after unroll)
        if (g == 0) {
#pragma unroll
            for (int mi = 0; mi < 4; ++mi)
#pragma unroll
                for (int i = 0; i < 4; ++i)
                    istash[mi][i] = sigmoid_f(acc[mi][i]);
        } else if (g == 8) {
#pragma unroll
            for (int mi = 0; mi < 4; ++mi)
#pragma unroll
                for (int i = 0; i < 4; ++i)
                    csum[mi][i] += tanh_f(acc[mi][i]) * istash[mi][i];
        } else if (g == 7) {
#pragma unroll
            for (int mi = 0; mi < 4; ++mi)
#pragma unroll
                for (int i = 0; i < 4; ++i) {
                    int n = mi * 16 + quad * 4 + i, kk = k0 + col;
                    float hv = sigmoid_f(acc[mi][i]) * tanh_f(csum[mi][i]);
                    if (last) outf[toff + n * 64 + kk] = hv;
                    else      h_out[toff + n * 64 + kk] = (_Float16)hv;
                }
        } else {                          // forget gates 1..6
#pragma unroll
            for (int mi = 0; mi < 4; ++mi)
#pragma unroll
                for (int i = 0; i < 4; ++i) {
                    int n = mi * 16 + quad * 4 + i, kk = k0 + col;
                    float val;
                    if (g == 1)      val = (float)ctb[n * 64 + kk];
                    else if (g == 2) val = (float)cc[n * 64 + kk];
                    else if (g == 3) val = (float)cta[n * 64 + kk];
                    else if (g == 4) val = (n > 0) ? (float)cc[(n - 1) * 64 + kk] : 0.0f;
                    else if (g == 5) val = gt32[(size_t)b * 4096 + n * 64 + kk];
                    else             val = gs32[(size_t)blk * 64 + kk];
                    csum[mi][i] += sigmoid_f(acc[mi][i]) * val;
                }
        }
    }

    if (!last) {                          // write new c (f16), each wave its slice
#pragma unroll
        for (int mi = 0; mi < 4; ++mi)
#pragma unroll
            for (int i = 0; i < 4; ++i) {
                int n = mi * 16 + quad * 4 + i, kk = k0 + col;
                c_out[toff + n * 64 + kk] = (_Float16)csum[mi][i];
            }
    }
}

// ---------------------------------------------------------------------------
extern "C" void kernel_launch(void* const* d_in, const int* in_sizes, int n_in,
                              void* d_out, int out_size, void* d_ws, size_t ws_size,
                              hipStream_t stream)
{
    const float* enc = (const float*)d_in[0];
    // d_in[1] (decoder_inputs) is unused by the reference
    const float* win = (const float*)d_in[2];
    const float* bin = (const float*)d_in[3];
    const float* U   = (const float*)d_in[4];
    const float* Wt  = (const float*)d_in[5];
    const float* Ws  = (const float*)d_in[6];
    const float* Zt  = (const float*)d_in[7];
    const float* Zs  = (const float*)d_in[8];
    const float* bb  = (const float*)d_in[9];
    float* out = (float*)d_out;
    char* ws = (char*)d_ws;

    _Float16* enc_hi = (_Float16*)(ws);                   // 16,777,216
    _Float16* enc_lo = (_Float16*)(ws + 16777216);        // 16,777,216
    _Float16* winT_h = (_Float16*)(ws + 33554432);        // 33,554,432 (dead after gemm)
    _Float16* winT_l = (_Float16*)(ws + 67108864);        // 33,554,432 (dead after gemm)
    float*    c0     = (float*)   (ws + 100663296);       // 33,030,144 (f32, for means)
    _Float16* hA     = (_Float16*)(ws + 133693440);       // 16,515,072 (= p = initial c)
    float*    gt32   = (float*)   (ws + 150208512);       // 524,288
    _Float16* gt16   = (_Float16*)(ws + 150732800);       // 262,144
    float*    gs32   = (float*)   (ws + 150994944);       // 516,096
    _Float16* gs16   = (_Float16*)(ws + 151511040);       // 258,048
    _Float16* WTp    = (_Float16*)(ws + 151769088);       // 516,096
    _Float16* ztile  = (_Float16*)(ws + 152285184);       // 8,192 ; end 152,293,376
    // after gemm_h0, winT_h/winT_l space is reused for the recur ping-pongs:
    _Float16* cB     = (_Float16*)(ws + 33554432);        // 16,515,072
    _Float16* cC     = (_Float16*)(ws + 50069504);        // 16,515,072 (< 67,108,864)
    _Float16* hB     = (_Float16*)(ws + 67108864);        // 16,515,072
    _Float16* hC     = (_Float16*)(ws + 83886080);        // 16,515,072 (< 100,663,296)

    prep_wt   <<<1008, 256, 0, stream>>>(Wt, Ws, U, Zt, Zs, WTp);
    zfill     <<<2, 256, 0, stream>>>(ztile);
    conv_enc  <<<4096, 256, 0, stream>>>(enc, enc_hi, enc_lo);
    transp_win<<<dim3(64, 64), 256, 0, stream>>>(win, winT_h, winT_l);
    gemm_h0   <<<512, 256, 0, stream>>>(enc_hi, enc_lo, winT_h, winT_l, bin, c0, hA);
    mean_t    <<<512, 256, 0, stream>>>(c0, gt32, gt16);
    mean_n    <<<504, 256, 0, stream>>>(c0, gs32, gs16);
    // step 1: c_in == h0 == hA (c = h initially)
    recur<<<2016, 256, 0, stream>>>(hA, hB, hA, cB, hA, gt16, gs16, gt32, gs32, WTp, bb, ztile, out, 0);
    recur<<<2016, 256, 0, stream>>>(hB, hC, cB, cC, hA, gt16, gs16, gt32, gs32, WTp, bb, ztile, out, 0);
    recur<<<2016, 256, 0, stream>>>(hC, nullptr, cC, nullptr, hA, gt16, gs16, gt32, gs32, WTp, bb, ztile, out, 1);
}

// Round 6
// 1137.112 us; speedup vs baseline: 2.0250x; 2.0250x over previous
//
#include <hip/hip_runtime.h>

typedef _Float16 v8h __attribute__((ext_vector_type(8)));
typedef float    v4f __attribute__((ext_vector_type(4)));

#define LO_SCALE 2048.0f
#define LO_INV   4.8828125e-4f

__device__ __forceinline__ float fast_rcp(float x) { return __builtin_amdgcn_rcpf(x); }
__device__ __forceinline__ float sigmoid_f(float x) { return fast_rcp(1.0f + __expf(-x)); }
__device__ __forceinline__ float tanh_f(float x) {
    float e = __expf(-2.0f * fabsf(x));
    float r = (1.0f - e) * fast_rcp(1.0f + e);
    return copysignf(r, x);
}

// ---------------------------------------------------------------------------
// prep: fused f16 weight matrix, STREAM-PACKED for the recur bf loads:
// WTp[g][ksl(4)][ks(14)][quad(4)][col(16)][j(8)] -> wave bf load = 1KB contig.
// Logical: WT[g][kout=ksl*16+col][k=ks*32+quad*8+j],
// K segments [Wt0|Wt1|Wt2|Ws|U|Zt|Zs[ZS_IDX[g]]].
// ---------------------------------------------------------------------------
__global__ void prep_wt(const float* __restrict__ Wt, const float* __restrict__ Ws,
                        const float* __restrict__ U,  const float* __restrict__ Zt,
                        const float* __restrict__ Zs, _Float16* __restrict__ WTp)
{
    int idx = blockIdx.x * 256 + threadIdx.x;
    if (idx >= 9 * 4 * 14 * 512) return;          // 258048
    int j    = idx & 7;
    int col  = (idx >> 3) & 15;
    int quad = (idx >> 7) & 3;
    int gksl = idx / 7168;
    int ks   = (idx - gksl * 7168) >> 9;
    int g    = gksl >> 2;
    int ksl  = gksl & 3;
    int kout = ksl * 16 + col;
    int k    = ks * 32 + quad * 8 + j;
    int seg  = k >> 6, kl = k & 63;
    const int zsidx[9] = {0, 1, 1, 3, 4, 5, 6, 7, 8};
    float v;
    if (seg < 3)       v = Wt[g * 12288 + (seg * 64 + kl) * 64 + kout];
    else if (seg == 3) v = Ws[g * 4096 + kl * 64 + kout];
    else if (seg == 4) v = U [g * 4096 + kl * 64 + kout];
    else if (seg == 5) v = Zt[g * 4096 + kl * 64 + kout];
    else               v = Zs[zsidx[g] * 4096 + kl * 64 + kout];
    WTp[idx] = (_Float16)v;
}

// ---------------------------------------------------------------------------
// f32 -> f16 hi/lo split of encoder inputs, zero-padded to 2048 rows
// ---------------------------------------------------------------------------
__global__ void conv_enc(const float* __restrict__ X,
                         _Float16* __restrict__ Yh, _Float16* __restrict__ Yl)
{
    long i = ((long)blockIdx.x * 256 + threadIdx.x) * 8;   // < 2048*4096
    v8h oh, ol;
    if (i < 2016L * 4096) {
        const float4* p = (const float4*)(X + i);
        float4 a = p[0], b = p[1];
        float xv[8] = {a.x, a.y, a.z, a.w, b.x, b.y, b.z, b.w};
#pragma unroll
        for (int j = 0; j < 8; ++j) {
            _Float16 hi = (_Float16)xv[j];
            oh[j] = hi;
            ol[j] = (_Float16)((xv[j] - (float)hi) * LO_SCALE);
        }
    } else {
#pragma unroll
        for (int j = 0; j < 8; ++j) { oh[j] = (_Float16)0.0f; ol[j] = (_Float16)0.0f; }
    }
    *(v8h*)(Yh + i) = oh;
    *(v8h*)(Yl + i) = ol;
}

// ---------------------------------------------------------------------------
// transpose weights_in [k][n] f32 -> winT hi/lo [n][k] f16
// ---------------------------------------------------------------------------
__global__ void transp_win(const float* __restrict__ W,
                           _Float16* __restrict__ Th, _Float16* __restrict__ Tl)
{
    __shared__ float tile[64][65];
    int k0 = blockIdx.x * 64, n0 = blockIdx.y * 64;
    int tid = threadIdx.x;
    int cc = tid & 63;
#pragma unroll
    for (int p = 0; p < 16; ++p) {
        int r = p * 4 + (tid >> 6);
        tile[cc][r] = W[(size_t)(k0 + r) * 4096 + n0 + cc];
    }
    __syncthreads();
#pragma unroll
    for (int p = 0; p < 16; ++p) {
        int r = p * 4 + (tid >> 6);
        float v = tile[r][cc];
        _Float16 hi = (_Float16)v;
        Th[(size_t)(n0 + r) * 4096 + k0 + cc] = hi;
        Tl[(size_t)(n0 + r) * 4096 + k0 + cc] = (_Float16)((v - (float)hi) * LO_SCALE);
    }
}

// ---------------------------------------------------------------------------
// h0 = enc @ winT^T + bias, compensated 3-pass f16 MFMA (f32-exact result)
// 128x128 tile, BK=32; writes f32 (c0) and f16 (hA)
// ---------------------------------------------------------------------------
__global__ __launch_bounds__(256, 2) void gemm_h0(
    const _Float16* __restrict__ Ah, const _Float16* __restrict__ Al,
    const _Float16* __restrict__ Bh, const _Float16* __restrict__ Bl,
    const float* __restrict__ bias, float* __restrict__ h0f, _Float16* __restrict__ h0h)
{
    __shared__ __attribute__((aligned(16))) _Float16 Ash[128 * 40];
    __shared__ __attribute__((aligned(16))) _Float16 Asl[128 * 40];
    __shared__ __attribute__((aligned(16))) _Float16 Bsh[128 * 40];
    __shared__ __attribute__((aligned(16))) _Float16 Bsl[128 * 40];
    int id = blockIdx.x;                 // 0..511
    int xcd = id & 7, local = id >> 3;   // local 0..63
    int nt = xcd * 4 + (local >> 4);     // 0..31
    int mt = local & 15;                 // 0..15
    int tid = threadIdx.x, wave = tid >> 6, lane = tid & 63;
    int col = lane & 15, quad = lane >> 4;

    v4f accm[2][8], accc[2][8];
#pragma unroll
    for (int mi = 0; mi < 2; ++mi)
#pragma unroll
        for (int ni = 0; ni < 8; ++ni) {
            v4f z = {0.f, 0.f, 0.f, 0.f};
            accm[mi][ni] = z; accc[mi][ni] = z;
        }

    for (int kt = 0; kt < 128; ++kt) {
        __syncthreads();
#pragma unroll
        for (int p = 0; p < 2; ++p) {
            int idx = p * 2048 + tid * 8;
            int r = idx >> 5, c = idx & 31;
            size_t ga = (size_t)(mt * 128 + r) * 4096 + kt * 32 + c;
            size_t gb = (size_t)(nt * 128 + r) * 4096 + kt * 32 + c;
            *(v8h*)(&Ash[r * 40 + c]) = *(const v8h*)(Ah + ga);
            *(v8h*)(&Asl[r * 40 + c]) = *(const v8h*)(Al + ga);
            *(v8h*)(&Bsh[r * 40 + c]) = *(const v8h*)(Bh + gb);
            *(v8h*)(&Bsl[r * 40 + c]) = *(const v8h*)(Bl + gb);
        }
        __syncthreads();
        v8h afh[2], afl[2];
#pragma unroll
        for (int mi = 0; mi < 2; ++mi) {
            afh[mi] = *(const v8h*)(&Ash[(wave * 32 + mi * 16 + col) * 40 + quad * 8]);
            afl[mi] = *(const v8h*)(&Asl[(wave * 32 + mi * 16 + col) * 40 + quad * 8]);
        }
#pragma unroll
        for (int ni = 0; ni < 8; ++ni) {
            v8h bfh = *(const v8h*)(&Bsh[(ni * 16 + col) * 40 + quad * 8]);
            v8h bfl = *(const v8h*)(&Bsl[(ni * 16 + col) * 40 + quad * 8]);
#pragma unroll
            for (int mi = 0; mi < 2; ++mi) {
                accm[mi][ni] = __builtin_amdgcn_mfma_f32_16x16x32_f16(afh[mi], bfh, accm[mi][ni], 0, 0, 0);
                accc[mi][ni] = __builtin_amdgcn_mfma_f32_16x16x32_f16(afl[mi], bfh, accc[mi][ni], 0, 0, 0);
                accc[mi][ni] = __builtin_amdgcn_mfma_f32_16x16x32_f16(afh[mi], bfl, accc[mi][ni], 0, 0, 0);
            }
        }
    }
#pragma unroll
    for (int mi = 0; mi < 2; ++mi)
#pragma unroll
        for (int ni = 0; ni < 8; ++ni)
#pragma unroll
            for (int i = 0; i < 4; ++i) {
                int row  = mt * 128 + wave * 32 + mi * 16 + quad * 4 + i;
                int ccol = nt * 128 + ni * 16 + col;
                if (row < 2016) {
                    float v = accm[mi][ni][i] + accc[mi][ni][i] * LO_INV + bias[ccol];
                    h0f[(size_t)row * 4096 + ccol] = v;
                    h0h[(size_t)row * 4096 + ccol] = (_Float16)v;
                }
            }
}

// ---------------------------------------------------------------------------
// g_t = mean over t (63);  g_s = mean over n (64)
// ---------------------------------------------------------------------------
__global__ void mean_t(const float* __restrict__ h0, float* __restrict__ gt32,
                       _Float16* __restrict__ gt16)
{
    int i = blockIdx.x * 256 + threadIdx.x;       // < 32*4096
    int b = i >> 12, c = i & 4095;
    float s = 0.f;
    for (int t = 0; t < 63; ++t) s += h0[((size_t)b * 63 + t) * 4096 + c];
    s *= (1.0f / 63.0f);
    gt32[i] = s; gt16[i] = (_Float16)s;
}

__global__ void mean_n(const float* __restrict__ h0, float* __restrict__ gs32,
                       _Float16* __restrict__ gs16)
{
    int i = blockIdx.x * 256 + threadIdx.x;       // < 2016*64
    int row = i >> 6, k = i & 63;
    float s = 0.f;
    for (int n = 0; n < 64; ++n) s += h0[(size_t)row * 4096 + n * 64 + k];
    s *= (1.0f / 64.0f);
    gs32[i] = s; gs16[i] = (_Float16)s;
}

// ---------------------------------------------------------------------------
// fused recurrent step, k-split, LDS-staged A, stream-packed weights,
// XCD-banded tile mapping. Block = 4 waves per (b,t); wave owns k-slice
// [wave*16, wave*16+16) and runs all 9 gates with the cell sum in registers.
// One barrier, no atomics, f32 c ping-pong.
// ---------------------------------------------------------------------------
__global__ __launch_bounds__(256, 3) void recur(
    const _Float16* __restrict__ h_in, _Float16* __restrict__ h_out,
    const float* __restrict__ c_in, float* __restrict__ c_out,
    const _Float16* __restrict__ p16, const _Float16* __restrict__ gt16,
    const _Float16* __restrict__ gs16, const float* __restrict__ gt32,
    const float* __restrict__ gs32, const _Float16* __restrict__ WTp,
    const float* __restrict__ bias9, float* __restrict__ outf, int last)
{
    __shared__ __attribute__((aligned(16))) _Float16 lds_htb[64 * 72];
    __shared__ __attribute__((aligned(16))) _Float16 lds_h  [65 * 72];   // row 0 = zeros
    __shared__ __attribute__((aligned(16))) _Float16 lds_hta[64 * 72];
    __shared__ __attribute__((aligned(16))) _Float16 lds_p  [64 * 72];

    // XCD banding: consecutive tiles (same b, neighboring t) stay on one XCD
    int blk = (blockIdx.x & 7) * 252 + (blockIdx.x >> 3);
    int b = blk / 63, t = blk - b * 63;
    size_t toff = (size_t)blk * 4096;
    int tid = threadIdx.x;
    int wave = tid >> 6, lane = tid & 63;
    int col = lane & 15, quad = lane >> 4;
    int k0 = wave * 16;                  // this wave's k-slice; ksl == wave

    v8h zero8;
#pragma unroll
    for (int j = 0; j < 8; ++j) zero8[j] = (_Float16)0.0f;

    // ---- stage h(t-1), h(t), h(t+1), p into LDS (stride 72)
    {
        const _Float16* s_htb = (t > 0)  ? h_in + toff - 4096 : nullptr;
        const _Float16* s_hta = (t < 62) ? h_in + toff + 4096 : nullptr;
#pragma unroll
        for (int p2 = 0; p2 < 2; ++p2) {
            int idx = p2 * 2048 + tid * 8;
            int r = idx >> 6, c = idx & 63;
            v8h v;
            v = s_htb ? *(const v8h*)(s_htb + idx) : zero8;
            *(v8h*)(&lds_htb[r * 72 + c]) = v;
            v = s_hta ? *(const v8h*)(s_hta + idx) : zero8;
            *(v8h*)(&lds_hta[r * 72 + c]) = v;
            *(v8h*)(&lds_h[(r + 1) * 72 + c]) = *(const v8h*)(h_in + toff + idx);
            *(v8h*)(&lds_p[r * 72 + c])       = *(const v8h*)(p16 + toff + idx);
        }
        if (tid < 8) *(v8h*)(&lds_h[tid * 8]) = zero8;    // zero row 0
    }
    __syncthreads();

    const _Float16* seglds[5] = {lds_htb, lds_h + 72, lds_hta, lds_h, lds_p};
    const _Float16* gtb = gt16 + (size_t)b * 4096;
    const _Float16* gsb = gs16 + (size_t)blk * 64;

    v4f csum[4], istash[4];
#pragma unroll
    for (int mi = 0; mi < 4; ++mi) {
        v4f z = {0.f, 0.f, 0.f, 0.f};
        csum[mi] = z; istash[mi] = z;
    }

    // gate order: 0(i), 1..6(forget), 8(c_n*i), 7(o -> h)
#pragma unroll
    for (int gi = 0; gi < 9; ++gi) {
        int g = (gi == 7) ? 8 : ((gi == 8) ? 7 : gi);
        const _Float16* wg = WTp + (size_t)(g * 4 + wave) * 7168;
        const float* bg = bias9 + g * 4096;

        v4f acc[4];
#pragma unroll
        for (int mi = 0; mi < 4; ++mi)
#pragma unroll
            for (int i = 0; i < 4; ++i)
                acc[mi][i] = bg[(mi * 16 + quad * 4 + i) * 64 + k0 + col];

#pragma unroll
        for (int ks = 0; ks < 14; ++ks) {
            int seg  = ks >> 1;
            int koff = (ks & 1) * 32 + quad * 8;
            v8h bf = *(const v8h*)(wg + ks * 512 + lane * 8);   // contiguous 1KB/wave
            v8h af[4];
            if (seg < 5) {
#pragma unroll
                for (int mi = 0; mi < 4; ++mi)
                    af[mi] = *(const v8h*)(seglds[seg] + (mi * 16 + col) * 72 + koff);
            } else if (seg == 5) {
#pragma unroll
                for (int mi = 0; mi < 4; ++mi)
                    af[mi] = *(const v8h*)(gtb + (mi * 16 + col) * 64 + koff);
            } else {
                v8h gv = *(const v8h*)(gsb + koff);     // broadcast over rows
#pragma unroll
                for (int mi = 0; mi < 4; ++mi) af[mi] = gv;
            }
#pragma unroll
            for (int mi = 0; mi < 4; ++mi)
                acc[mi] = __builtin_amdgcn_mfma_f32_16x16x32_f16(af[mi], bf, acc[mi], 0, 0, 0);
        }

        // ---- epilogue for this gate (g is compile-time after unroll)
        if (g == 0) {
#pragma unroll
            for (int mi = 0; mi < 4; ++mi)
#pragma unroll
                for (int i = 0; i < 4; ++i)
                    istash[mi][i] = sigmoid_f(acc[mi][i]);
        } else if (g == 8) {
#pragma unroll
            for (int mi = 0; mi < 4; ++mi)
#pragma unroll
                for (int i = 0; i < 4; ++i)
                    csum[mi][i] += tanh_f(acc[mi][i]) * istash[mi][i];
        } else if (g == 7) {
#pragma unroll
            for (int mi = 0; mi < 4; ++mi)
#pragma unroll
                for (int i = 0; i < 4; ++i) {
                    int n = mi * 16 + quad * 4 + i, kk = k0 + col;
                    float hv = sigmoid_f(acc[mi][i]) * tanh_f(csum[mi][i]);
                    if (last) outf[toff + n * 64 + kk] = hv;
                    else      h_out[toff + n * 64 + kk] = (_Float16)hv;
                }
        } else {                          // forget gates 1..6
#pragma unroll
            for (int mi = 0; mi < 4; ++mi)
#pragma unroll
                for (int i = 0; i < 4; ++i) {
                    int n = mi * 16 + quad * 4 + i, kk = k0 + col;
                    float val;
                    if (g == 1)      val = (t > 0)  ? c_in[toff - 4096 + n * 64 + kk] : 0.0f;
                    else if (g == 2) val = c_in[toff + n * 64 + kk];
                    else if (g == 3) val = (t < 62) ? c_in[toff + 4096 + n * 64 + kk] : 0.0f;
                    else if (g == 4) val = (n > 0)  ? c_in[toff + (n - 1) * 64 + kk] : 0.0f;
                    else if (g == 5) val = gt32[(size_t)b * 4096 + n * 64 + kk];
                    else             val = gs32[(size_t)blk * 64 + kk];
                    csum[mi][i] += sigmoid_f(acc[mi][i]) * val;
                }
        }
    }

    if (!last) {                          // write new c (f32), each wave its slice
#pragma unroll
        for (int mi = 0; mi < 4; ++mi)
#pragma unroll
            for (int i = 0; i < 4; ++i) {
                int n = mi * 16 + quad * 4 + i, kk = k0 + col;
                c_out[toff + n * 64 + kk] = csum[mi][i];
            }
    }
}

// ---------------------------------------------------------------------------
extern "C" void kernel_launch(void* const* d_in, const int* in_sizes, int n_in,
                              void* d_out, int out_size, void* d_ws, size_t ws_size,
                              hipStream_t stream)
{
    const float* enc = (const float*)d_in[0];
    // d_in[1] (decoder_inputs) is unused by the reference
    const float* win = (const float*)d_in[2];
    const float* bin = (const float*)d_in[3];
    const float* U   = (const float*)d_in[4];
    const float* Wt  = (const float*)d_in[5];
    const float* Ws  = (const float*)d_in[6];
    const float* Zt  = (const float*)d_in[7];
    const float* Zs  = (const float*)d_in[8];
    const float* bb  = (const float*)d_in[9];
    float* out = (float*)d_out;
    char* ws = (char*)d_ws;

    _Float16* enc_hi = (_Float16*)(ws);                   // 16,777,216 (dead after gemm)
    _Float16* enc_lo = (_Float16*)(ws + 16777216);        // 16,777,216 (dead after gemm)
    _Float16* winT_h = (_Float16*)(ws + 33554432);        // 33,554,432 (dead after gemm)
    _Float16* winT_l = (_Float16*)(ws + 67108864);        // 33,554,432 (dead after gemm)
    float*    c0     = (float*)   (ws + 100663296);       // 33,030,144 (= initial c, f32)
    _Float16* hA     = (_Float16*)(ws + 133693440);       // 16,515,072 (= p = h0)
    float*    gt32   = (float*)   (ws + 150208512);       // 524,288
    _Float16* gt16   = (_Float16*)(ws + 150732800);       // 262,144
    float*    gs32   = (float*)   (ws + 150994944);       // 516,096
    _Float16* gs16   = (_Float16*)(ws + 151511040);       // 258,048
    _Float16* WTp    = (_Float16*)(ws + 151769088);       // 516,096 ; end 152,285,184
    // recur-phase overlays (all source regions dead after gemm_h0):
    _Float16* hB     = (_Float16*)(ws);                   // 16,515,072 (enc_hi)
    _Float16* hC     = (_Float16*)(ws + 16777216);        // 16,515,072 (enc_lo)
    float*    cB     = (float*)   (ws + 33554432);        // 33,030,144 (winT_h)
    float*    cC     = (float*)   (ws + 67108864);        // 33,030,144 (winT_l)

    prep_wt   <<<1008, 256, 0, stream>>>(Wt, Ws, U, Zt, Zs, WTp);
    conv_enc  <<<4096, 256, 0, stream>>>(enc, enc_hi, enc_lo);
    transp_win<<<dim3(64, 64), 256, 0, stream>>>(win, winT_h, winT_l);
    gemm_h0   <<<512, 256, 0, stream>>>(enc_hi, enc_lo, winT_h, winT_l, bin, c0, hA);
    mean_t    <<<512, 256, 0, stream>>>(c0, gt32, gt16);
    mean_n    <<<504, 256, 0, stream>>>(c0, gs32, gs16);
    // step 1: c_in = c0 (f32 h0 exactly)
    recur<<<2016, 256, 0, stream>>>(hA, hB, c0, cB, hA, gt16, gs16, gt32, gs32, WTp, bb, out, 0);
    recur<<<2016, 256, 0, stream>>>(hB, hC, cB, cC, hA, gt16, gs16, gt32, gs32, WTp, bb, out, 0);
    recur<<<2016, 256, 0, stream>>>(hC, nullptr, cC, nullptr, hA, gt16, gs16, gt32, gs32, WTp, bb, out, 1);
}

// Round 7
// 698.581 us; speedup vs baseline: 3.2962x; 1.6277x over previous
//
#include <hip/hip_runtime.h>

typedef _Float16 v8h __attribute__((ext_vector_type(8)));
typedef float    v4f __attribute__((ext_vector_type(4)));

#define LO_SCALE 2048.0f
#define LO_INV   4.8828125e-4f

__device__ __forceinline__ float fast_rcp(float x) { return __builtin_amdgcn_rcpf(x); }
__device__ __forceinline__ float sigmoid_f(float x) { return fast_rcp(1.0f + __expf(-x)); }
__device__ __forceinline__ float tanh_f(float x) {
    float e = __expf(-2.0f * fabsf(x));
    float r = (1.0f - e) * fast_rcp(1.0f + e);
    return copysignf(r, x);
}

// ---------------------------------------------------------------------------
// prep: fused f16 weights, packed [ksl(4)][ks(16)][g(9)][quad(4)][col(16)][j(8)]
// so recur's 9 inner-gate bf loads are contiguous. K = 512:
//   k<448 : segments [Wt0|Wt1|Wt2|Ws|U|Zt|Zs[ZS_IDX[g]]]
//   k>=448: bias^T (b[g][n=k-448][kout]) -- bias enters via MFMA with A=delta
// ---------------------------------------------------------------------------
__global__ void prep_wt(const float* __restrict__ Wt, const float* __restrict__ Ws,
                        const float* __restrict__ U,  const float* __restrict__ Zt,
                        const float* __restrict__ Zs, const float* __restrict__ bb,
                        _Float16* __restrict__ WTp)
{
    int idx = blockIdx.x * 256 + threadIdx.x;
    if (idx >= 4 * 16 * 9 * 512) return;          // 294912
    int j    = idx & 7;
    int col  = (idx >> 3) & 15;
    int quad = (idx >> 7) & 3;
    int g    = (idx >> 9) % 9;
    int ks   = (idx / 4608) & 15;
    int ksl  = idx / 73728;
    int kout = ksl * 16 + col;
    int k    = ks * 32 + quad * 8 + j;
    const int zsidx[9] = {0, 1, 1, 3, 4, 5, 6, 7, 8};
    float v;
    if (k >= 448) {
        int n = k - 448;
        v = bb[g * 4096 + n * 64 + kout];
    } else {
        int seg = k >> 6, kl = k & 63;
        if (seg < 3)       v = Wt[g * 12288 + (seg * 64 + kl) * 64 + kout];
        else if (seg == 3) v = Ws[g * 4096 + kl * 64 + kout];
        else if (seg == 4) v = U [g * 4096 + kl * 64 + kout];
        else if (seg == 5) v = Zt[g * 4096 + kl * 64 + kout];
        else               v = Zs[zsidx[g] * 4096 + kl * 64 + kout];
    }
    WTp[idx] = (_Float16)v;
}

// ---------------------------------------------------------------------------
// f32 -> f16 hi/lo split of encoder inputs, zero-padded to 2048 rows
// ---------------------------------------------------------------------------
__global__ void conv_enc(const float* __restrict__ X,
                         _Float16* __restrict__ Yh, _Float16* __restrict__ Yl)
{
    long i = ((long)blockIdx.x * 256 + threadIdx.x) * 8;   // < 2048*4096
    v8h oh, ol;
    if (i < 2016L * 4096) {
        const float4* p = (const float4*)(X + i);
        float4 a = p[0], b = p[1];
        float xv[8] = {a.x, a.y, a.z, a.w, b.x, b.y, b.z, b.w};
#pragma unroll
        for (int j = 0; j < 8; ++j) {
            _Float16 hi = (_Float16)xv[j];
            oh[j] = hi;
            ol[j] = (_Float16)((xv[j] - (float)hi) * LO_SCALE);
        }
    } else {
#pragma unroll
        for (int j = 0; j < 8; ++j) { oh[j] = (_Float16)0.0f; ol[j] = (_Float16)0.0f; }
    }
    *(v8h*)(Yh + i) = oh;
    *(v8h*)(Yl + i) = ol;
}

// ---------------------------------------------------------------------------
// transpose weights_in [k][n] f32 -> winT hi/lo [n][k] f16
// ---------------------------------------------------------------------------
__global__ void transp_win(const float* __restrict__ W,
                           _Float16* __restrict__ Th, _Float16* __restrict__ Tl)
{
    __shared__ float tile[64][65];
    int k0 = blockIdx.x * 64, n0 = blockIdx.y * 64;
    int tid = threadIdx.x;
    int cc = tid & 63;
#pragma unroll
    for (int p = 0; p < 16; ++p) {
        int r = p * 4 + (tid >> 6);
        tile[cc][r] = W[(size_t)(k0 + r) * 4096 + n0 + cc];
    }
    __syncthreads();
#pragma unroll
    for (int p = 0; p < 16; ++p) {
        int r = p * 4 + (tid >> 6);
        float v = tile[r][cc];
        _Float16 hi = (_Float16)v;
        Th[(size_t)(n0 + r) * 4096 + k0 + cc] = hi;
        Tl[(size_t)(n0 + r) * 4096 + k0 + cc] = (_Float16)((v - (float)hi) * LO_SCALE);
    }
}

// ---------------------------------------------------------------------------
// h0 = enc @ winT^T + bias, compensated 3-pass f16 MFMA (f32-exact result)
// 128x128 tile, BK=32; writes f32 (c0) and f16 (hA)
// ---------------------------------------------------------------------------
__global__ __launch_bounds__(256, 2) void gemm_h0(
    const _Float16* __restrict__ Ah, const _Float16* __restrict__ Al,
    const _Float16* __restrict__ Bh, const _Float16* __restrict__ Bl,
    const float* __restrict__ bias, float* __restrict__ h0f, _Float16* __restrict__ h0h)
{
    __shared__ __attribute__((aligned(16))) _Float16 Ash[128 * 40];
    __shared__ __attribute__((aligned(16))) _Float16 Asl[128 * 40];
    __shared__ __attribute__((aligned(16))) _Float16 Bsh[128 * 40];
    __shared__ __attribute__((aligned(16))) _Float16 Bsl[128 * 40];
    int id = blockIdx.x;                 // 0..511
    int xcd = id & 7, local = id >> 3;   // local 0..63
    int nt = xcd * 4 + (local >> 4);     // 0..31
    int mt = local & 15;                 // 0..15
    int tid = threadIdx.x, wave = tid >> 6, lane = tid & 63;
    int col = lane & 15, quad = lane >> 4;

    v4f accm[2][8], accc[2][8];
#pragma unroll
    for (int mi = 0; mi < 2; ++mi)
#pragma unroll
        for (int ni = 0; ni < 8; ++ni) {
            v4f z = {0.f, 0.f, 0.f, 0.f};
            accm[mi][ni] = z; accc[mi][ni] = z;
        }

    for (int kt = 0; kt < 128; ++kt) {
        __syncthreads();
#pragma unroll
        for (int p = 0; p < 2; ++p) {
            int idx = p * 2048 + tid * 8;
            int r = idx >> 5, c = idx & 31;
            size_t ga = (size_t)(mt * 128 + r) * 4096 + kt * 32 + c;
            size_t gb = (size_t)(nt * 128 + r) * 4096 + kt * 32 + c;
            *(v8h*)(&Ash[r * 40 + c]) = *(const v8h*)(Ah + ga);
            *(v8h*)(&Asl[r * 40 + c]) = *(const v8h*)(Al + ga);
            *(v8h*)(&Bsh[r * 40 + c]) = *(const v8h*)(Bh + gb);
            *(v8h*)(&Bsl[r * 40 + c]) = *(const v8h*)(Bl + gb);
        }
        __syncthreads();
        v8h afh[2], afl[2];
#pragma unroll
        for (int mi = 0; mi < 2; ++mi) {
            afh[mi] = *(const v8h*)(&Ash[(wave * 32 + mi * 16 + col) * 40 + quad * 8]);
            afl[mi] = *(const v8h*)(&Asl[(wave * 32 + mi * 16 + col) * 40 + quad * 8]);
        }
#pragma unroll
        for (int ni = 0; ni < 8; ++ni) {
            v8h bfh = *(const v8h*)(&Bsh[(ni * 16 + col) * 40 + quad * 8]);
            v8h bfl = *(const v8h*)(&Bsl[(ni * 16 + col) * 40 + quad * 8]);
#pragma unroll
            for (int mi = 0; mi < 2; ++mi) {
                accm[mi][ni] = __builtin_amdgcn_mfma_f32_16x16x32_f16(afh[mi], bfh, accm[mi][ni], 0, 0, 0);
                accc[mi][ni] = __builtin_amdgcn_mfma_f32_16x16x32_f16(afl[mi], bfh, accc[mi][ni], 0, 0, 0);
                accc[mi][ni] = __builtin_amdgcn_mfma_f32_16x16x32_f16(afh[mi], bfl, accc[mi][ni], 0, 0, 0);
            }
        }
    }
#pragma unroll
    for (int mi = 0; mi < 2; ++mi)
#pragma unroll
        for (int ni = 0; ni < 8; ++ni)
#pragma unroll
            for (int i = 0; i < 4; ++i) {
                int row  = mt * 128 + wave * 32 + mi * 16 + quad * 4 + i;
                int ccol = nt * 128 + ni * 16 + col;
                if (row < 2016) {
                    float v = accm[mi][ni][i] + accc[mi][ni][i] * LO_INV + bias[ccol];
                    h0f[(size_t)row * 4096 + ccol] = v;
                    h0h[(size_t)row * 4096 + ccol] = (_Float16)v;
                }
            }
}

// ---------------------------------------------------------------------------
// g_t = mean over t (63);  g_s = mean over n (64)
// ---------------------------------------------------------------------------
__global__ void mean_t(const float* __restrict__ h0, float* __restrict__ gt32,
                       _Float16* __restrict__ gt16)
{
    int i = blockIdx.x * 256 + threadIdx.x;       // < 32*4096
    int b = i >> 12, c = i & 4095;
    float s = 0.f;
    for (int t = 0; t < 63; ++t) s += h0[((size_t)b * 63 + t) * 4096 + c];
    s *= (1.0f / 63.0f);
    gt32[i] = s; gt16[i] = (_Float16)s;
}

__global__ void mean_n(const float* __restrict__ h0, float* __restrict__ gs32,
                       _Float16* __restrict__ gs16)
{
    int i = blockIdx.x * 256 + threadIdx.x;       // < 2016*64
    int row = i >> 6, k = i & 63;
    float s = 0.f;
    for (int n = 0; n < 64; ++n) s += h0[(size_t)row * 4096 + n * 64 + k];
    s *= (1.0f / 64.0f);
    gs32[i] = s; gs16[i] = (_Float16)s;
}

// ---------------------------------------------------------------------------
// fused recurrent step, ks-OUTER / gates-INNER:
// Block = 4 waves per (b,t); wave owns k-slice [wave*16, wave*16+16).
// acc[9][4] holds all 9 gate pre-activations (flat, constant-indexed).
// A-fragments loaded once per ks (shared by 9 gates); bias via K-extension
// (ks 14,15: A = delta(k-448, n), B = bias^T). One barrier, no atomics.
// ---------------------------------------------------------------------------
__global__ __launch_bounds__(256, 2) void recur(
    const _Float16* __restrict__ h_in, _Float16* __restrict__ h_out,
    const float* __restrict__ c_in, float* __restrict__ c_out,
    const _Float16* __restrict__ p16, const _Float16* __restrict__ gt16,
    const _Float16* __restrict__ gs16, const float* __restrict__ gt32,
    const float* __restrict__ gs32, const _Float16* __restrict__ WTp,
    float* __restrict__ outf, int last)
{
    __shared__ __attribute__((aligned(16))) _Float16 lds_htb[64 * 72];
    __shared__ __attribute__((aligned(16))) _Float16 lds_h  [65 * 72];   // row 0 = zeros
    __shared__ __attribute__((aligned(16))) _Float16 lds_hta[64 * 72];
    __shared__ __attribute__((aligned(16))) _Float16 lds_p  [64 * 72];

    // XCD banding: consecutive tiles (same b, neighboring t) stay on one XCD
    int blk = (blockIdx.x & 7) * 252 + (blockIdx.x >> 3);
    int b = blk / 63, t = blk - b * 63;
    size_t toff = (size_t)blk * 4096;
    int tid = threadIdx.x;
    int wave = tid >> 6, lane = tid & 63;
    int col = lane & 15, quad = lane >> 4;
    int k0 = wave * 16;                  // this wave's k-slice; ksl == wave

    v8h zero8;
#pragma unroll
    for (int j = 0; j < 8; ++j) zero8[j] = (_Float16)0.0f;

    // ---- stage h(t-1), h(t), h(t+1), p into LDS (stride 72)
    {
        const _Float16* s_htb = (t > 0)  ? h_in + toff - 4096 : nullptr;
        const _Float16* s_hta = (t < 62) ? h_in + toff + 4096 : nullptr;
#pragma unroll
        for (int p2 = 0; p2 < 2; ++p2) {
            int idx = p2 * 2048 + tid * 8;
            int r = idx >> 6, c = idx & 63;
            v8h v;
            v = s_htb ? *(const v8h*)(s_htb + idx) : zero8;
            *(v8h*)(&lds_htb[r * 72 + c]) = v;
            v = s_hta ? *(const v8h*)(s_hta + idx) : zero8;
            *(v8h*)(&lds_hta[r * 72 + c]) = v;
            *(v8h*)(&lds_h[(r + 1) * 72 + c]) = *(const v8h*)(h_in + toff + idx);
            *(v8h*)(&lds_p[r * 72 + c])       = *(const v8h*)(p16 + toff + idx);
        }
        if (tid < 8) *(v8h*)(&lds_h[tid * 8]) = zero8;    // zero row 0
    }
    __syncthreads();

    const _Float16* seglds[5] = {lds_htb, lds_h + 72, lds_hta, lds_h, lds_p};
    const _Float16* gtb = gt16 + (size_t)b * 4096;
    const _Float16* gsb = gs16 + (size_t)blk * 64;

    v4f acc[9][4];
#pragma unroll
    for (int g = 0; g < 9; ++g)
#pragma unroll
        for (int mi = 0; mi < 4; ++mi) {
            v4f z = {0.f, 0.f, 0.f, 0.f};
            acc[g][mi] = z;
        }

    const _Float16* wbase = WTp + (size_t)wave * 73728 + quad * 128 + col * 8;

#pragma unroll
    for (int ks = 0; ks < 16; ++ks) {
        int seg  = ks >> 1;
        int koff = (ks & 1) * 32 + quad * 8;
        v8h af[4];
        if (ks < 10) {                    // LDS segments: htb, h, hta, h(n-1), p
#pragma unroll
            for (int mi = 0; mi < 4; ++mi)
                af[mi] = *(const v8h*)(seglds[seg] + (mi * 16 + col) * 72 + koff);
        } else if (ks < 12) {             // g_t (global, L2-hot)
#pragma unroll
            for (int mi = 0; mi < 4; ++mi)
                af[mi] = *(const v8h*)(gtb + (mi * 16 + col) * 64 + koff);
        } else if (ks < 14) {             // g_s broadcast over rows
            v8h gv = *(const v8h*)(gsb + koff);
#pragma unroll
            for (int mi = 0; mi < 4; ++mi) af[mi] = gv;
        } else {                          // bias delta: A[n][k] = (k-448 == n)
#pragma unroll
            for (int mi = 0; mi < 4; ++mi) {
                int tgt = mi * 16 + col - ((ks - 14) * 32 + quad * 8);
                v8h z;
#pragma unroll
                for (int j = 0; j < 8; ++j)
                    z[j] = (_Float16)((tgt == j) ? 1.0f : 0.0f);
                af[mi] = z;
            }
        }
        const _Float16* wk = wbase + ks * 4608;
#pragma unroll
        for (int g = 0; g < 9; ++g) {
            v8h bf = *(const v8h*)(wk + g * 512);
#pragma unroll
            for (int mi = 0; mi < 4; ++mi)
                acc[g][mi] = __builtin_amdgcn_mfma_f32_16x16x32_f16(af[mi], bf, acc[g][mi], 0, 0, 0);
        }
    }

    // ---- fused epilogue: c = sum of gate*partner, h = o * tanh(c)
    const float* cb  = c_in + toff - 4096;
    const float* ccp = c_in + toff;
    const float* ca  = c_in + toff + 4096;
    const float* gtp = gt32 + (size_t)b * 4096;
    float gsv = gs32[(size_t)blk * 64 + k0 + col];

#pragma unroll
    for (int mi = 0; mi < 4; ++mi)
#pragma unroll
        for (int i = 0; i < 4; ++i) {
            int n = mi * 16 + quad * 4 + i, kk = k0 + col;
            int o = n * 64 + kk;
            float s = tanh_f(acc[8][mi][i]) * sigmoid_f(acc[0][mi][i]);
            s += sigmoid_f(acc[1][mi][i]) * ((t > 0)  ? cb[o]  : 0.0f);
            s += sigmoid_f(acc[2][mi][i]) * ccp[o];
            s += sigmoid_f(acc[3][mi][i]) * ((t < 62) ? ca[o]  : 0.0f);
            s += sigmoid_f(acc[4][mi][i]) * ((n > 0)  ? ccp[o - 64] : 0.0f);
            s += sigmoid_f(acc[5][mi][i]) * gtp[o];
            s += sigmoid_f(acc[6][mi][i]) * gsv;
            float hv = sigmoid_f(acc[7][mi][i]) * tanh_f(s);
            if (last) outf[toff + o] = hv;
            else {
                h_out[toff + o] = (_Float16)hv;
                c_out[toff + o] = s;
            }
        }
}

// ---------------------------------------------------------------------------
extern "C" void kernel_launch(void* const* d_in, const int* in_sizes, int n_in,
                              void* d_out, int out_size, void* d_ws, size_t ws_size,
                              hipStream_t stream)
{
    const float* enc = (const float*)d_in[0];
    // d_in[1] (decoder_inputs) is unused by the reference
    const float* win = (const float*)d_in[2];
    const float* bin = (const float*)d_in[3];
    const float* U   = (const float*)d_in[4];
    const float* Wt  = (const float*)d_in[5];
    const float* Ws  = (const float*)d_in[6];
    const float* Zt  = (const float*)d_in[7];
    const float* Zs  = (const float*)d_in[8];
    const float* bb  = (const float*)d_in[9];
    float* out = (float*)d_out;
    char* ws = (char*)d_ws;

    _Float16* enc_hi = (_Float16*)(ws);                   // 16,777,216 (dead after gemm)
    _Float16* enc_lo = (_Float16*)(ws + 16777216);        // 16,777,216 (dead after gemm)
    _Float16* winT_h = (_Float16*)(ws + 33554432);        // 33,554,432 (dead after gemm)
    _Float16* winT_l = (_Float16*)(ws + 67108864);        // 33,554,432 (dead after gemm)
    float*    c0     = (float*)   (ws + 100663296);       // 33,030,144 (= initial c, f32)
    _Float16* hA     = (_Float16*)(ws + 133693440);       // 16,515,072 (= p = h0)
    float*    gt32   = (float*)   (ws + 150208512);       // 524,288
    _Float16* gt16   = (_Float16*)(ws + 150732800);       // 262,144
    float*    gs32   = (float*)   (ws + 150994944);       // 516,096
    _Float16* gs16   = (_Float16*)(ws + 151511040);       // 258,048
    _Float16* WTp    = (_Float16*)(ws + 151769088);       // 589,824 ; end 152,358,912
    // recur-phase overlays (all source regions dead after gemm_h0):
    _Float16* hB     = (_Float16*)(ws);                   // 16,515,072 (enc_hi)
    _Float16* hC     = (_Float16*)(ws + 16777216);        // 16,515,072 (enc_lo)
    float*    cB     = (float*)   (ws + 33554432);        // 33,030,144 (winT_h)
    float*    cC     = (float*)   (ws + 67108864);        // 33,030,144 (winT_l)

    prep_wt   <<<1152, 256, 0, stream>>>(Wt, Ws, U, Zt, Zs, bb, WTp);
    conv_enc  <<<4096, 256, 0, stream>>>(enc, enc_hi, enc_lo);
    transp_win<<<dim3(64, 64), 256, 0, stream>>>(win, winT_h, winT_l);
    gemm_h0   <<<512, 256, 0, stream>>>(enc_hi, enc_lo, winT_h, winT_l, bin, c0, hA);
    mean_t    <<<512, 256, 0, stream>>>(c0, gt32, gt16);
    mean_n    <<<504, 256, 0, stream>>>(c0, gs32, gs16);
    // step 1: c_in = c0 (f32 h0 exactly)
    recur<<<2016, 256, 0, stream>>>(hA, hB, c0, cB, hA, gt16, gs16, gt32, gs32, WTp, out, 0);
    recur<<<2016, 256, 0, stream>>>(hB, hC, cB, cC, hA, gt16, gs16, gt32, gs32, WTp, out, 0);
    recur<<<2016, 256, 0, stream>>>(hC, nullptr, cC, nullptr, hA, gt16, gs16, gt32, gs32, WTp, out, 1);
}